// Round 1
// baseline (1039.022 us; speedup 1.0000x reference)
//
#include <hip/hip_runtime.h>
#include <math.h>

namespace {
constexpr int kH = 8192;        // hidden dim (K of GEMM)
constexpr int kE = 256;         // experts (N of GEMM)
constexpr int kTopK = 8;
constexpr int kTok = 8192;      // B*S token rows (M of GEMM)
constexpr int kBT = 16;         // tokens per block
constexpr int kKT = 32;         // k-slice staged in LDS
constexpr int kPad = 18;        // xs inner stride in doubles (even -> 16B-aligned rows, padded)
constexpr int kIdxOff = kTok * kTopK;          // 65536
constexpr int kLogitsOff = 2 * kTok * kTopK;   // 131072
}

// One block = 16 tokens x 256 experts, fp64 accumulation.
// 256 threads: lane = tid&63 owns experts lane*4..lane*4+3; wave tr = tid>>6
// owns tokens tr*4..tr*4+3. So each wave holds 4 complete token rows -> fused
// top-k via shfl butterfly, no second kernel, no workspace.
__global__ __launch_bounds__(256, 2)
void moe_router_kernel(const float* __restrict__ x,
                       const float* __restrict__ Wr,
                       float* __restrict__ out)
{
    __shared__ double xs[kKT][kPad];   // xs[j][t] = (double)x[tok0+t][k0+j]

    const int tid  = threadIdx.x;
    const int lane = tid & 63;
    const int tr   = tid >> 6;          // wave id 0..3
    const int tok0 = blockIdx.x * kBT;

    double acc[4][4];
    #pragma unroll
    for (int t = 0; t < 4; ++t)
        #pragma unroll
        for (int m = 0; m < 4; ++m) acc[t][m] = 0.0;

    // staging map: thread loads one float2 of x per k-tile
    const int t_s = tid >> 4;           // 0..15
    const int j_s = (tid & 15) << 1;    // 0..30
    const float* xsrc = x + (size_t)(tok0 + t_s) * kH + j_s;

    for (int k0 = 0; k0 < kH; k0 += kKT) {
        float2 xv2 = *reinterpret_cast<const float2*>(xsrc + k0);
        __syncthreads();                // previous tile fully consumed
        xs[j_s + 0][t_s] = (double)xv2.x;
        xs[j_s + 1][t_s] = (double)xv2.y;
        __syncthreads();

        const float* wrow = Wr + (size_t)k0 * kE + (lane << 2);
        #pragma unroll 8
        for (int j = 0; j < kKT; ++j) {
            float4 w4 = *reinterpret_cast<const float4*>(wrow);
            wrow += kE;
            const double wd0 = (double)w4.x;
            const double wd1 = (double)w4.y;
            const double wd2 = (double)w4.z;
            const double wd3 = (double)w4.w;
            const double* xrow = &xs[j][tr << 2];
            #pragma unroll
            for (int t = 0; t < 4; ++t) {
                const double xv = xrow[t];
                acc[t][0] = fma(xv, wd0, acc[t][0]);
                acc[t][1] = fma(xv, wd1, acc[t][1]);
                acc[t][2] = fma(xv, wd2, acc[t][2]);
                acc[t][3] = fma(xv, wd3, acc[t][3]);
            }
        }
    }

    // ---- write logits (fp32), coalesced float4 per lane ----
    #pragma unroll
    for (int t = 0; t < 4; ++t) {
        const int token = tok0 + (tr << 2) + t;
        float4 f4;
        f4.x = (float)acc[t][0];
        f4.y = (float)acc[t][1];
        f4.z = (float)acc[t][2];
        f4.w = (float)acc[t][3];
        *reinterpret_cast<float4*>(out + kLogitsOff + (size_t)token * kE + (lane << 2)) = f4;
    }

    // ---- fused top-8 + softmax, one token row per wave-iteration ----
    #pragma unroll
    for (int t = 0; t < 4; ++t) {
        double v0 = acc[t][0], v1 = acc[t][1], v2 = acc[t][2], v3 = acc[t][3];
        double mx = 0.0, ssum = 0.0, myv = 0.0;
        int myi = 0;
        #pragma unroll
        for (int r = 0; r < kTopK; ++r) {
            // lane-local argmax (ascending scan + strict '>' => lowest index on ties)
            double bv = v0; int bi = (lane << 2);
            if (v1 > bv) { bv = v1; bi = (lane << 2) + 1; }
            if (v2 > bv) { bv = v2; bi = (lane << 2) + 2; }
            if (v3 > bv) { bv = v3; bi = (lane << 2) + 3; }
            // wave argmax butterfly; total order (value desc, index asc) ->
            // all 64 lanes converge to the identical winner.
            #pragma unroll
            for (int off = 32; off > 0; off >>= 1) {
                double ov = __shfl_xor(bv, off, 64);
                int    oi = __shfl_xor(bi, off, 64);
                if (ov > bv || (ov == bv && oi < bi)) { bv = ov; bi = oi; }
            }
            if (r == 0) mx = bv;
            ssum += exp(bv - mx);
            if (lane == r) { myv = bv; myi = bi; }   // lane r keeps r-th result
            if ((bi >> 2) == lane) {                 // owner removes the winner
                const int m = bi & 3;
                if      (m == 0) v0 = -1.0e300;
                else if (m == 1) v1 = -1.0e300;
                else if (m == 2) v2 = -1.0e300;
                else             v3 = -1.0e300;
            }
        }
        if (lane < kTopK) {
            const int token = tok0 + (tr << 2) + t;
            out[token * kTopK + lane]           = (float)(exp(myv - mx) / ssum);
            out[kIdxOff + token * kTopK + lane] = (float)myi;   // index as fp32 value
        }
    }
}

extern "C" void kernel_launch(void* const* d_in, const int* in_sizes, int n_in,
                              void* d_out, int out_size, void* d_ws, size_t ws_size,
                              hipStream_t stream) {
    const float* x  = (const float*)d_in[0];   // [4,2048,8192] fp32
    const float* Wr = (const float*)d_in[1];   // [8192,256] fp32
    float* out = (float*)d_out;                // weights | indices | logits (fp32 view)
    (void)in_sizes; (void)n_in; (void)out_size; (void)d_ws; (void)ws_size;

    dim3 grid(kTok / kBT);   // 512 blocks
    dim3 block(256);
    hipLaunchKernelGGL(moe_router_kernel, grid, block, 0, stream, x, Wr, out);
}

// Round 2
// 706.927 us; speedup vs baseline: 1.4698x; 1.4698x over previous
//
#include <hip/hip_runtime.h>
#include <math.h>
#include <float.h>

namespace {
constexpr int kH = 8192;        // hidden (K)
constexpr int kE = 256;         // experts (N)
constexpr int kTopK = 8;
constexpr int kTok = 8192;      // B*S rows (M)
constexpr int kIdxOff = kTok * kTopK;          // 65536
constexpr int kLogitsOff = 2 * kTok * kTopK;   // 131072
// GEMM tiling
constexpr int kBT = 64;                  // tokens per block
constexpr int kKC = 4;                   // split-K chunks
constexpr int kKchunk = kH / kKC;        // 2048
constexpr int kKT = 32;                  // k per LDS tile
constexpr int kPadT = 68;                // padded token stride (17 float4: aligned + ~conflict-free)
constexpr int kCand = 16;                // top-k candidates kept for refinement
constexpr float kEps = 1e-3f;            // fp32-ordering trust margin (~500x fp32 error)
// ws layout (bytes): Wt fp32 [256][8192] @0 (8MB); partials 1..3 @8MB (24MB)
constexpr size_t kWtFloats = (size_t)kE * kH;           // 2,097,152
constexpr size_t kPartFloats = (size_t)kTok * kE;       // 2,097,152 per chunk
}

// ---------------- Kernel A: W[k][e] -> Wt[e][k] (for coalesced refinement) ----
__global__ __launch_bounds__(1024)
void transpose_w(const float* __restrict__ W, float* __restrict__ Wt) {
    __shared__ float tile[32][33];
    const int k0 = blockIdx.x * 32, e0 = blockIdx.y * 32;
    const int tx = threadIdx.x, ty = threadIdx.y;
    tile[ty][tx] = W[(size_t)(k0 + ty) * kE + (e0 + tx)];
    __syncthreads();
    Wt[(size_t)(e0 + ty) * kH + (k0 + tx)] = tile[tx][ty];
}

// ---------------- Kernel B: split-K fp32 GEMM ------------------------------
// block = 64 tokens x 256 experts x 2048 k.  256 thr: lane owns 4 experts,
// wave owns 16 tokens -> acc[16][4] (64-way FMA ILP per W float4 load).
__global__ __launch_bounds__(256, 2)
void router_gemm(const float* __restrict__ x, const float* __restrict__ Wr,
                 float* __restrict__ p0, float* __restrict__ pws)
{
    __shared__ float xs[kKT][kPadT];
    const int tid  = threadIdx.x;
    const int lane = tid & 63;
    const int w    = tid >> 6;
    const int t0   = blockIdx.x * kBT;
    const int kc   = blockIdx.y;
    const int kbase = kc * kKchunk;

    float acc[16][4];
    #pragma unroll
    for (int t = 0; t < 16; ++t)
        #pragma unroll
        for (int m = 0; m < 4; ++m) acc[t][m] = 0.f;

    // staging map: thread -> token tt, two float4 slots (s4, s4+4)
    const int tt = tid >> 2;
    const int s4 = tid & 3;
    const float* xrow = x + (size_t)(t0 + tt) * kH + kbase;

    for (int k0 = 0; k0 < kKchunk; k0 += kKT) {
        const float4 a = *reinterpret_cast<const float4*>(xrow + k0 + (s4 << 2));
        const float4 b = *reinterpret_cast<const float4*>(xrow + k0 + (s4 << 2) + 16);
        __syncthreads();                 // previous tile fully consumed
        xs[(s4 << 2) + 0][tt] = a.x;
        xs[(s4 << 2) + 1][tt] = a.y;
        xs[(s4 << 2) + 2][tt] = a.z;
        xs[(s4 << 2) + 3][tt] = a.w;
        xs[(s4 << 2) + 16][tt] = b.x;
        xs[(s4 << 2) + 17][tt] = b.y;
        xs[(s4 << 2) + 18][tt] = b.z;
        xs[(s4 << 2) + 19][tt] = b.w;
        __syncthreads();

        const float* wp = Wr + (size_t)(kbase + k0) * kE + (lane << 2);
        #pragma unroll 8
        for (int j = 0; j < kKT; ++j) {
            const float4 wv = *reinterpret_cast<const float4*>(wp);
            wp += kE;
            const float* xj = &xs[j][w << 4];
            const float4 xa = *reinterpret_cast<const float4*>(xj);
            const float4 xb = *reinterpret_cast<const float4*>(xj + 4);
            const float4 xc = *reinterpret_cast<const float4*>(xj + 8);
            const float4 xd = *reinterpret_cast<const float4*>(xj + 12);
            const float xv[16] = {xa.x, xa.y, xa.z, xa.w, xb.x, xb.y, xb.z, xb.w,
                                  xc.x, xc.y, xc.z, xc.w, xd.x, xd.y, xd.z, xd.w};
            #pragma unroll
            for (int t = 0; t < 16; ++t) {
                acc[t][0] = fmaf(xv[t], wv.x, acc[t][0]);
                acc[t][1] = fmaf(xv[t], wv.y, acc[t][1]);
                acc[t][2] = fmaf(xv[t], wv.z, acc[t][2]);
                acc[t][3] = fmaf(xv[t], wv.w, acc[t][3]);
            }
        }
    }

    float* dst = (kc == 0) ? p0 : (pws + (size_t)(kc - 1) * kPartFloats);
    #pragma unroll
    for (int t = 0; t < 16; ++t) {
        const int token = t0 + (w << 4) + t;
        float4 o;
        o.x = acc[t][0]; o.y = acc[t][1]; o.z = acc[t][2]; o.w = acc[t][3];
        *reinterpret_cast<float4*>(dst + (size_t)token * kE + (lane << 2)) = o;
    }
}

// ---------------- Kernel C: combine + select + (rare) fp64 refine ----------
__global__ __launch_bounds__(64)
void combine_select(const float* __restrict__ x, const float* __restrict__ Wt,
                    const float* __restrict__ pws, float* __restrict__ out)
{
    const int lane = threadIdx.x;
    const int row  = blockIdx.x;
    float* logits = out + kLogitsOff;
    const size_t rb = (size_t)row * kE + (lane << 2);

    float4 s = *reinterpret_cast<const float4*>(logits + rb);   // partial 0
    #pragma unroll
    for (int p = 0; p < kKC - 1; ++p) {
        const float4 q = *reinterpret_cast<const float4*>(pws + (size_t)p * kPartFloats + rb);
        s.x += q.x; s.y += q.y; s.z += q.z; s.w += q.w;
    }
    *reinterpret_cast<float4*>(logits + rb) = s;                // final logits

    float v0 = s.x, v1 = s.y, v2 = s.z, v3 = s.w;
    float myv = -FLT_MAX; int myi = -1;
    #pragma unroll
    for (int r = 0; r < kCand; ++r) {
        float bv = v0; int bi = (lane << 2);
        if (v1 > bv) { bv = v1; bi = (lane << 2) + 1; }
        if (v2 > bv) { bv = v2; bi = (lane << 2) + 2; }
        if (v3 > bv) { bv = v3; bi = (lane << 2) + 3; }
        #pragma unroll
        for (int off = 32; off > 0; off >>= 1) {
            const float ov = __shfl_xor(bv, off, 64);
            const int   oi = __shfl_xor(bi, off, 64);
            if (ov > bv || (ov == bv && oi < bi)) { bv = ov; bi = oi; }
        }
        if (lane == r) { myv = bv; myi = bi; }
        if ((bi >> 2) == lane) {                    // owner removes winner
            const int m = bi & 3;
            if      (m == 0) v0 = -FLT_MAX;
            else if (m == 1) v1 = -FLT_MAX;
            else if (m == 2) v2 = -FLT_MAX;
            else             v3 = -FLT_MAX;
        }
    }

    // adjacent gaps among ranks 0..8 (pairs (0,1)..(7,8)): trust fp32 if all wide
    const float nv = __shfl_down(myv, 1, 64);
    const unsigned long long amb = __ballot(lane < 8 && (myv - nv) < kEps);

    if (amb == 0ull) {
        const float m = __shfl(myv, 0, 64);
        const float e = (lane < kTopK) ? expf(myv - m) : 0.f;
        float t = e;
        #pragma unroll
        for (int off = 1; off < 8; off <<= 1) t += __shfl_xor(t, off, 64);
        if (lane < kTopK) {
            out[(size_t)row * kTopK + lane]           = e / t;
            out[kIdxOff + (size_t)row * kTopK + lane] = (float)myi;
        }
    } else {
        // fp64 recompute of the 16 candidates (coalesced: whole wave per column)
        const float* xr = x + (size_t)row * kH;
        double dv = -1.0e300;
        #pragma unroll 1
        for (int c = 0; c < kCand; ++c) {
            const int idx = __shfl(myi, c, 64);
            const float* wr = Wt + (size_t)idx * kH;
            double a = 0.0;
            for (int k = (lane << 2); k < kH; k += 256) {
                const float4 xv = *reinterpret_cast<const float4*>(xr + k);
                const float4 wv = *reinterpret_cast<const float4*>(wr + k);
                a = fma((double)xv.x, (double)wv.x, a);
                a = fma((double)xv.y, (double)wv.y, a);
                a = fma((double)xv.z, (double)wv.z, a);
                a = fma((double)xv.w, (double)wv.w, a);
            }
            #pragma unroll
            for (int off = 32; off > 0; off >>= 1) a += __shfl_xor(a, off, 64);
            if (lane == c) dv = a;
        }
        double cv = dv; int ci = myi;
        double mx = 0.0, ssum = 0.0, keepv = 0.0; int keepi = 0;
        #pragma unroll 1
        for (int r = 0; r < kTopK; ++r) {
            double bv = cv; int bi = ci;
            #pragma unroll
            for (int off = 32; off > 0; off >>= 1) {
                const double ov = __shfl_xor(bv, off, 64);
                const int    oi = __shfl_xor(bi, off, 64);
                if (ov > bv || (ov == bv && oi < bi)) { bv = ov; bi = oi; }
            }
            if (r == 0) mx = bv;
            ssum += exp(bv - mx);
            if (lane == r) { keepv = bv; keepi = bi; }
            if (ci == bi) cv = -1.0e300;            // owner (indices unique) removes
        }
        if (lane < kTopK) {
            out[(size_t)row * kTopK + lane]           = (float)(exp(keepv - mx) / ssum);
            out[kIdxOff + (size_t)row * kTopK + lane] = (float)keepi;
        }
    }
}

extern "C" void kernel_launch(void* const* d_in, const int* in_sizes, int n_in,
                              void* d_out, int out_size, void* d_ws, size_t ws_size,
                              hipStream_t stream) {
    const float* x  = (const float*)d_in[0];
    const float* Wr = (const float*)d_in[1];
    float* out = (float*)d_out;
    float* Wt  = (float*)d_ws;                      // 8 MB
    float* pws = (float*)d_ws + kWtFloats;          // 24 MB (3 partials)
    (void)in_sizes; (void)n_in; (void)out_size; (void)ws_size;

    hipLaunchKernelGGL(transpose_w, dim3(kH / 32, kE / 32), dim3(32, 32), 0, stream, Wr, Wt);
    hipLaunchKernelGGL(router_gemm, dim3(kTok / kBT, kKC), dim3(256), 0, stream,
                       x, Wr, out + kLogitsOff, pws);
    hipLaunchKernelGGL(combine_select, dim3(kTok), dim3(64), 0, stream, x, Wt, pws, out);
}